// Round 4
// baseline (188.500 us; speedup 1.0000x reference)
//
#include <hip/hip_runtime.h>

#define EPS 1e-5f
#define SLOPE 0.01f

typedef __attribute__((ext_vector_type(4))) float f32x4;
typedef __attribute__((ext_vector_type(8))) short bf16x8;

__device__ __forceinline__ short f2bf(float f) {
    unsigned u = __float_as_uint(f);
    unsigned r = (u + 0x7FFFu + ((u >> 16) & 1u)) >> 16;
    return (short)r;
}
__device__ __forceinline__ float lrelu(float v) { return v >= 0.f ? v : SLOPE * v; }

// async global->LDS staging (width 16 / width 4). LDS dst: uniform base +
// lane*size; global src is PER-LANE (carries the row gather).
__device__ __forceinline__ void gload16(const float* g, float* l) {
    __builtin_amdgcn_global_load_lds(
        (const __attribute__((address_space(1))) unsigned*)g,
        (__attribute__((address_space(3))) unsigned*)l, 16, 0, 0);
}
__device__ __forceinline__ void gload4(const float* g, float* l) {
    __builtin_amdgcn_global_load_lds(
        (const __attribute__((address_space(1))) unsigned*)g,
        (__attribute__((address_space(3))) unsigned*)l, 4, 0, 0);
}

// counted vmcnt wait; n is compile-time-foldable after full unroll
__device__ __forceinline__ void wait_vm(int n) {
    switch (n) {
    case 0:  asm volatile("s_waitcnt vmcnt(0)" ::: "memory"); break;
    case 2:  asm volatile("s_waitcnt vmcnt(2)" ::: "memory"); break;
    case 4:  asm volatile("s_waitcnt vmcnt(4)" ::: "memory"); break;
    case 6:  asm volatile("s_waitcnt vmcnt(6)" ::: "memory"); break;
    case 8:  asm volatile("s_waitcnt vmcnt(8)" ::: "memory"); break;
    case 10: asm volatile("s_waitcnt vmcnt(10)" ::: "memory"); break;
    case 12: asm volatile("s_waitcnt vmcnt(12)" ::: "memory"); break;
    case 16: asm volatile("s_waitcnt vmcnt(16)" ::: "memory"); break;
    case 20: asm volatile("s_waitcnt vmcnt(20)" ::: "memory"); break;
    case 24: asm volatile("s_waitcnt vmcnt(24)" ::: "memory"); break;
    case 32: asm volatile("s_waitcnt vmcnt(32)" ::: "memory"); break;
    case 40: asm volatile("s_waitcnt vmcnt(40)" ::: "memory"); break;
    default: asm volatile("s_waitcnt vmcnt(0)" ::: "memory"); break;
    }
}

template<int XT, int XVALID, int ST, bool XA16>
constexpr int tile_ops(int t) {
    if (((XVALID % 32) != 0) && t == XT - 1) return 0;   // partial: reg path
    if (t < XT && !XA16) return 8;                       // width-4 x8
    return 2;                                            // width-16 x2
}
template<int XT, int XVALID, int ST, bool XA16, int CT>
constexpr int chunk_ops(int c) {
    int s = 0;
    for (int g = 0; g < CT; ++g) {
        int t = c * CT + g;
        if (t < XT + ST) s += tile_ops<XT, XVALID, ST, XA16>(t);
    }
    return s;
}

// ---------------------------------------------------------------------------
// Wt prep (unchanged layouts; y1 region of Wt2 already has zero rows 129..159
// which matches the y1 column padding to 160). Also zeros stats block.
// ---------------------------------------------------------------------------
__global__ void prep(const float* __restrict__ W1, const float* __restrict__ W2,
                     const float* __restrict__ W3,
                     short* __restrict__ Wt1, short* __restrict__ Wt2,
                     short* __restrict__ Wt3, float* __restrict__ stats)
{
    int id = blockIdx.x * 256 + threadIdx.x;
    if (id < 2048) stats[id] = 0.f;
    if (id < 144 * 800) {
        int n = id / 800, kv = id - n * 800;
        float v = 0.f; int ks = -1;
        if (kv < 258) ks = kv; else if (kv >= 288) ks = 258 + (kv - 288);
        if (ks >= 0 && n < 129) v = W1[ks * 129 + n];
        Wt1[n * 800 + kv] = f2bf(v);
    }
    if (id < 64 * 416) {
        int n = id / 416, kv = id - n * 416;
        float v = 0.f; int ks = -1;
        if (kv < 129) ks = kv; else if (kv >= 160) ks = 129 + (kv - 160);
        if (ks >= 0) v = W2[ks * 64 + n];
        Wt2[n * 416 + kv] = f2bf(v);
    }
    if (id < 48 * 192) {
        int n = id / 192, kv = id - n * 192;
        float v = 0.f;
        if (n < 34) v = W3[kv * 34 + n];
        Wt3[n * 192 + kv] = f2bf(v);
    }
}

// ---------------------------------------------------------------------------
// MFMA stage with async LDS staging. 4 waves/block, each wave owns 16 rows and
// a PRIVATE LDS region (no __syncthreads in the K loop). A-tiles staged by
// global_load_lds (per-lane gathered src), double-buffered in chunks of CT;
// counted vmcnt waits at chunk boundaries.
// ---------------------------------------------------------------------------
template<int XD, int XVALID, int XT, int SD, int ST, int NT, int NVALID, int OD,
         bool XA16, int CT, int NBUF, int MINW, bool BN, bool STATS, bool PRELB>
__global__ __launch_bounds__(256, MINW)
void mfma_stage(const float* __restrict__ xsrc, const float* __restrict__ skip,
                const int* __restrict__ idx, const short* __restrict__ Wt,
                const float* __restrict__ bias,
                const float* __restrict__ bnsc, const float* __restrict__ bnsh,
                float* __restrict__ out, float* __restrict__ ssum,
                float* __restrict__ ssq)
{
    constexpr int T  = XT + ST;
    constexpr int KV = 32 * T;
    constexpr int NC = (T + CT - 1) / CT;
    constexpr int NPAD = NT * 16;
    constexpr bool HASPART = (XVALID % 32) != 0;

    __shared__ __align__(16) float abuf[NBUF * CT * 4 * 512];

    const int tid  = threadIdx.x;
    const int wave = tid >> 6, lane = tid & 63;
    const int lr = lane & 15;                    // A row-in-16 / D col
    const int kg = lane >> 4;                    // k-group
    const int row16 = (blockIdx.x * 4 + wave) * 16;
    const int n0 = blockIdx.y * NPAD;
    const int myrow = row16 + lr;
    const int grow = idx[myrow];
    const float* xrow = xsrc + grow * XD;
    const float* srow = skip + myrow * SD;
    const short* wtl = Wt + (n0 + lr) * KV;

    // ---- staging issue for chunk c ----
    auto issue = [&](int c) {
#pragma unroll
        for (int g = 0; g < CT; ++g) {
            const int t = c * CT + g;
            if (t >= T) continue;
            if (HASPART && t == XT - 1) continue;        // partial: reg path
            const int slot = (c % NBUF) * CT + g;
            float* base = &abuf[(slot * 4 + wave) * 512];
            if (t < XT) {
                const float* src = xrow + t * 32 + kg * 8;
                if (XA16) {
                    gload16(src,     base);
                    gload16(src + 4, base + 256);
                } else {
#pragma unroll
                    for (int e = 0; e < 8; ++e)
                        gload4(src + e, base + e * 64);
                }
            } else {
                const float* src = srow + (t - XT) * 32 + kg * 8;
                gload16(src,     base);
                gload16(src + 4, base + 256);
            }
        }
    };

    f32x4 acc[NT];
#pragma unroll
    for (int nt = 0; nt < NT; ++nt) acc[nt] = (f32x4){0.f, 0.f, 0.f, 0.f};

    issue(0);
    if (NC > 1) issue(1);

    bf16x8 Bf[PRELB ? T * NT : 1];
    if (PRELB) {
#pragma unroll
        for (int t = 0; t < T; ++t)
#pragma unroll
            for (int nt = 0; nt < NT; ++nt)
                Bf[t * NT + nt] = *(const bf16x8*)(wtl + t * 32 + kg * 8 + nt * 16 * KV);
    }

#pragma unroll
    for (int c = 0; c < NC; ++c) {
        wait_vm((c + 1 < NC) ? chunk_ops<XT, XVALID, ST, XA16, CT>(c + 1) : 0);
#pragma unroll
        for (int g = 0; g < CT; ++g) {
            const int t = c * CT + g;
            if (t >= T) continue;
            const int slot = (c % NBUF) * CT + g;
            const float* base = &abuf[(slot * 4 + wave) * 512];
            float v[8];
            if (HASPART && t == XT - 1) {                // guarded reg path
                const int kb = t * 32 + kg * 8;
#pragma unroll
                for (int e = 0; e < 8; ++e) {
                    float f = 0.f;
                    if (kb + e < XVALID) {
                        f = xrow[kb + e];
                        if (BN) f = lrelu(fmaf(f, bnsc[kb + e], bnsh[kb + e]));
                    }
                    v[e] = f;
                }
            } else {
                if (t < XT && !XA16) {
#pragma unroll
                    for (int e = 0; e < 8; ++e) v[e] = base[e * 64 + lane];
                } else {
                    f32x4 lo = *(const f32x4*)(base + lane * 4);
                    f32x4 hi = *(const f32x4*)(base + 256 + lane * 4);
#pragma unroll
                    for (int e = 0; e < 4; ++e) { v[e] = lo[e]; v[e + 4] = hi[e]; }
                }
                if (BN && t < XT) {
                    const int kb = t * 32 + kg * 8;
                    f32x4 c0 = *(const f32x4*)(bnsc + kb);
                    f32x4 c1 = *(const f32x4*)(bnsc + kb + 4);
                    f32x4 h0 = *(const f32x4*)(bnsh + kb);
                    f32x4 h1 = *(const f32x4*)(bnsh + kb + 4);
#pragma unroll
                    for (int e = 0; e < 4; ++e) {
                        v[e]     = lrelu(fmaf(v[e],     c0[e], h0[e]));
                        v[e + 4] = lrelu(fmaf(v[e + 4], c1[e], h1[e]));
                    }
                }
            }
            bf16x8 a;
#pragma unroll
            for (int e = 0; e < 8; ++e) a[e] = f2bf(v[e]);
#pragma unroll
            for (int nt = 0; nt < NT; ++nt) {
                bf16x8 b;
                if (PRELB) b = Bf[t * NT + nt];
                else b = *(const bf16x8*)(wtl + t * 32 + kg * 8 + nt * 16 * KV);
                acc[nt] = __builtin_amdgcn_mfma_f32_16x16x32_bf16(a, b, acc[nt], 0, 0, 0);
            }
        }
        if (c + 2 < NC) issue(c + 2);
    }

    // ---- bias + store ----
#pragma unroll
    for (int nt = 0; nt < NT; ++nt) {
        const int n = n0 + nt * 16 + lr;
        const float bv = (n < NVALID) ? bias[n] : 0.f;
#pragma unroll
        for (int r = 0; r < 4; ++r) acc[nt][r] += bv;
        if (n < NVALID) {
#pragma unroll
            for (int r = 0; r < 4; ++r)
                out[(row16 + kg * 4 + r) * OD + n] = acc[nt][r];
        }
    }

    // ---- stats (overlay scratch LDS over abuf; staging is fully consumed) ----
    if (STATS) {
        float* ls = abuf;
        __syncthreads();
        for (int i = tid; i < 2 * NPAD; i += 256) ls[i] = 0.f;
        __syncthreads();
#pragma unroll
        for (int nt = 0; nt < NT; ++nt) {
            float s = acc[nt][0] + acc[nt][1] + acc[nt][2] + acc[nt][3];
            float q = acc[nt][0]*acc[nt][0] + acc[nt][1]*acc[nt][1]
                    + acc[nt][2]*acc[nt][2] + acc[nt][3]*acc[nt][3];
            s += __shfl_xor(s, 16, 64);
            s += __shfl_xor(s, 32, 64);
            q += __shfl_xor(q, 16, 64);
            q += __shfl_xor(q, 32, 64);
            if (lane < 16) {
                atomicAdd(&ls[nt * 16 + lr], s);
                atomicAdd(&ls[NPAD + nt * 16 + lr], q);
            }
        }
        __syncthreads();
        if (tid < NPAD) {
            atomicAdd(&ssum[n0 + tid], ls[tid]);
            atomicAdd(&ssq[n0 + tid], ls[NPAD + tid]);
        }
    }
}

__global__ void finalize_bn(const float* __restrict__ sum,
                            const float* __restrict__ sq,
                            const float* __restrict__ g,
                            const float* __restrict__ be,
                            float* __restrict__ scale,
                            float* __restrict__ shift,
                            int C, int CPAD, float invN)
{
    int c = blockIdx.x * blockDim.x + threadIdx.x;
    if (c < CPAD) {
        if (c < C) {
            float m   = sum[c] * invN;
            float var = fmaf(-m, m, sq[c] * invN);
            float rs  = rsqrtf(var + EPS);
            float sc  = rs * g[c];
            scale[c] = sc;
            shift[c] = fmaf(-m, sc, be[c]);
        } else {
            scale[c] = 0.f;   // pad channels -> A value forced to 0
            shift[c] = 0.f;
        }
    }
}

extern "C" void kernel_launch(void* const* d_in, const int* in_sizes, int n_in,
                              void* d_out, int out_size, void* d_ws, size_t ws_size,
                              hipStream_t stream) {
    const float* feats = (const float*)d_in[0];
    const float* skip1 = (const float*)d_in[1];
    const float* skip2 = (const float*)d_in[2];
    const float* skip3 = (const float*)d_in[3];
    const int*   idx1  = (const int*)d_in[4];
    const int*   idx2  = (const int*)d_in[5];
    const int*   idx3  = (const int*)d_in[6];
    const float* W1    = (const float*)d_in[7];
    const float* b1    = (const float*)d_in[8];
    const float* g1    = (const float*)d_in[9];
    const float* be1   = (const float*)d_in[10];
    const float* W2    = (const float*)d_in[11];
    const float* b2    = (const float*)d_in[12];
    const float* g2    = (const float*)d_in[13];
    const float* be2   = (const float*)d_in[14];
    const float* W3    = (const float*)d_in[15];
    const float* b3    = (const float*)d_in[16];

    float* ws   = (float*)d_ws;
    float* sum1 = ws;        float* sq1 = ws + 256;
    float* sc1  = ws + 512;  float* sh1 = ws + 768;
    float* sum2 = ws + 1024; float* sq2 = ws + 1280;
    float* sc2  = ws + 1536; float* sh2 = ws + 1792;
    short* Wt1  = (short*)(ws + 2048);        // 144*800
    short* Wt2  = Wt1 + 144 * 800;            // 64*416
    short* Wt3  = Wt2 + 64 * 416;             // 48*192
    float* y1   = ws + 2048 + (144 * 800 + 64 * 416 + 48 * 192) / 2;  // [16384][160]
    float* y2   = y1 + 16384 * 160;                                   // [65536][64]
    float* outp = (float*)d_out;

    prep<<<450, 256, 0, stream>>>(W1, W2, W3, Wt1, Wt2, Wt3, ws);

    // stage 1: M=16384, x=feats(258, 8B-aligned rows -> width-4 staging),
    // skip3(512), N=129 in 3 chunks, y1 padded to 160 cols
    mfma_stage<258, 258, 9, 512, 16, 3, 129, 160, false, 5, 2, 2, false, true, false>
        <<<dim3(256, 3), 256, 0, stream>>>(feats, skip3, idx1, Wt1, b1,
                                           nullptr, nullptr, y1, sum1, sq1);
    finalize_bn<<<1, 256, 0, stream>>>(sum1, sq1, g1, be1, sc1, sh1,
                                       129, 160, 1.f / 16384.f);

    // stage 2: M=65536, x=y1(160 padded, BN pad-channels zeroed), skip2(256), N=64
    mfma_stage<160, 160, 5, 256, 8, 4, 64, 64, true, 4, 2, 2, true, true, false>
        <<<dim3(1024, 1), 256, 0, stream>>>(y1, skip2, idx2, Wt2, b2,
                                            sc1, sh1, y2, sum2, sq2);
    finalize_bn<<<1, 256, 0, stream>>>(sum2, sq2, g2, be2, sc2, sh2,
                                       64, 64, 1.f / 65536.f);

    // stage 3: M=262144, x=y2(64), skip1(128), N=34; all-upfront staging,
    // B preloaded to regs, single vmcnt(0)
    mfma_stage<64, 64, 2, 128, 4, 3, 34, 34, true, 6, 1, 3, true, false, true>
        <<<dim3(4096, 1), 256, 0, stream>>>(y2, skip1, idx3, Wt3, b3,
                                            sc2, sh2, outp, nullptr, nullptr);
}

// Round 5
// 152.832 us; speedup vs baseline: 1.2334x; 1.2334x over previous
//
#include <hip/hip_runtime.h>

#define EPS 1e-5f
#define SLOPE 0.01f

typedef __attribute__((ext_vector_type(4))) float f32x4;
typedef __attribute__((ext_vector_type(8))) short bf16x8;

__device__ __forceinline__ short f2bf(float f) {
    unsigned u = __float_as_uint(f);
    unsigned r = (u + 0x7FFFu + ((u >> 16) & 1u)) >> 16;
    return (short)r;
}
__device__ __forceinline__ float lrelu(float v) { return v >= 0.f ? v : SLOPE * v; }

__device__ __forceinline__ void gload16(const float* g, float* l) {
    __builtin_amdgcn_global_load_lds(
        (const __attribute__((address_space(1))) unsigned*)g,
        (__attribute__((address_space(3))) unsigned*)l, 16, 0, 0);
}
__device__ __forceinline__ void gload4(const float* g, float* l) {
    __builtin_amdgcn_global_load_lds(
        (const __attribute__((address_space(1))) unsigned*)g,
        (__attribute__((address_space(3))) unsigned*)l, 4, 0, 0);
}
__device__ __forceinline__ void wait_vm(int n) {
    switch (n) {
    case 0:  asm volatile("s_waitcnt vmcnt(0)" ::: "memory"); break;
    case 4:  asm volatile("s_waitcnt vmcnt(4)" ::: "memory"); break;
    case 16: asm volatile("s_waitcnt vmcnt(16)" ::: "memory"); break;
    default: asm volatile("s_waitcnt vmcnt(0)" ::: "memory"); break;
    }
}

// ---------------------------------------------------------------------------
// Wt prep: W -> Wt[n][kv] bf16, zero-padded. Virtual-K layouts:
//  S1 (KV=800): kv 0..257 = W1 rows 0..257 (feats), 258..287 = 0,
//               288..799 = W1 rows 258..769 (skip3)
//  S2 (KV=448): kv 0..128 = W2 rows 0..128 (y1), 129..191 = 0 (y1 pad),
//               192..447 = W2 rows 129..384 (skip2)
//  S3 (KV=192): kv = W3 rows (y2 64 | skip1 128), exact
// Also zeros the 2048-float stats block.
// ---------------------------------------------------------------------------
__global__ void prep(const float* __restrict__ W1, const float* __restrict__ W2,
                     const float* __restrict__ W3,
                     short* __restrict__ Wt1, short* __restrict__ Wt2,
                     short* __restrict__ Wt3, float* __restrict__ stats)
{
    int id = blockIdx.x * 256 + threadIdx.x;
    if (id < 2048) stats[id] = 0.f;
    if (id < 144 * 800) {
        int n = id / 800, kv = id - n * 800;
        float v = 0.f; int ks = -1;
        if (kv < 258) ks = kv; else if (kv >= 288) ks = 258 + (kv - 288);
        if (ks >= 0 && n < 129) v = W1[ks * 129 + n];
        Wt1[n * 800 + kv] = f2bf(v);
    }
    if (id < 64 * 448) {
        int n = id / 448, kv = id - n * 448;
        float v = 0.f; int ks = -1;
        if (kv < 129) ks = kv; else if (kv >= 192) ks = 129 + (kv - 192);
        if (ks >= 0) v = W2[ks * 64 + n];
        Wt2[n * 448 + kv] = f2bf(v);
    }
    if (id < 48 * 192) {
        int n = id / 192, kv = id - n * 192;
        float v = 0.f;
        if (n < 34) v = W3[kv * 34 + n];
        Wt3[n * 192 + kv] = f2bf(v);
    }
}

// ---------------------------------------------------------------------------
// MFMA stage. 4 waves/block, wave owns 16 rows. K processed in 64-float
// chunks staged into per-wave LDS [16][64]f32 (double-buffered) by
// global_load_lds whose instructions cover ROW-CONTIGUOUS 256B spans (the
// source address carries both the gather and an XOR swizzle so fragment
// ds_reads are ~4-way-conflict-free). No intra-loop barriers: each wave
// reads only LDS it staged; counted vmcnt per wave.
// Swizzle: LDS slot s (16B units within a row's 64-float chunk) holds source
// chunk (s&~7)|((s&7)^(r&6)).
// ---------------------------------------------------------------------------
template<int XD, int XVALID, int XTILES, int SD, int NT, int NVALID, int OD,
         int KV, bool XA16, bool BN, bool STATS>
__global__ __launch_bounds__(256, 4)
void mfma_stage(const float* __restrict__ xsrc, const float* __restrict__ skip,
                const int* __restrict__ idx, const short* __restrict__ Wt,
                const float* __restrict__ bias,
                const float* __restrict__ bnsc, const float* __restrict__ bnsh,
                float* __restrict__ out, float* __restrict__ ssum,
                float* __restrict__ ssq)
{
    constexpr int NCX = XVALID / 64;          // full 64-float x chunks
    constexpr int NCS = SD / 64;              // skip chunks
    constexpr int NC  = NCX + NCS;
    constexpr bool HASPART = (XVALID % 64) != 0;
    constexpr int NPAD = NT * 16;

    __shared__ __align__(16) float abuf[4][2][1024];   // 32 KB

    const int tid  = threadIdx.x;
    const int wave = tid >> 6, lane = tid & 63;
    const int lr = lane & 15;                 // fragment row within wave tile
    const int kg = lane >> 4;                 // k-group
    const int row0w = (blockIdx.x * 4 + wave) * 16;    // wave's first row
    const int n0 = blockIdx.y * NPAD;
    const short* wtl = Wt + (n0 + lr) * KV;

    // per-lane gathered row pointers for the 4-row-group staging instrs
    const float* prow[4];
    if (XA16) {
#pragma unroll
        for (int q = 0; q < 4; ++q)
            prow[q] = xsrc + (size_t)idx[row0w + q * 4 + (lane >> 4)] * XD;
    }

    f32x4 acc[NT];
#pragma unroll
    for (int nt = 0; nt < NT; ++nt) acc[nt] = (f32x4){0.f, 0.f, 0.f, 0.f};

    // ---- partial x tile (stage 1 only): direct guarded loads, own row ----
    if (HASPART) {
        const float* xr = xsrc + (size_t)idx[row0w + lr] * XD;
        constexpr int kb = (XTILES - 1) * 32;
        float v[8];
#pragma unroll
        for (int e = 0; e < 8; ++e) {
            int ks = kb + kg * 8 + e;
            float f = 0.f;
            if (ks < XVALID) {
                f = xr[ks];
                if (BN) f = lrelu(fmaf(f, bnsc[ks], bnsh[ks]));
            }
            v[e] = f;
        }
        bf16x8 a;
#pragma unroll
        for (int e = 0; e < 8; ++e) a[e] = f2bf(v[e]);
#pragma unroll
        for (int nt = 0; nt < NT; ++nt) {
            bf16x8 b = *(const bf16x8*)(wtl + kb + kg * 8 + nt * 16 * KV);
            acc[nt] = __builtin_amdgcn_mfma_f32_16x16x32_bf16(a, b, acc[nt], 0, 0, 0);
        }
    }

    // ---- staging issue for chunk c ----
    auto issue = [&](int c) {
        float* wb = &abuf[wave][c & 1][0];
        if (c < NCX) {
            if (XA16) {
#pragma unroll
                for (int q = 0; q < 4; ++q) {
                    const int rl = q * 4 + (lane >> 4);
                    const int s  = lane & 15;
                    const int cf = (s & ~7) | ((s & 7) ^ (rl & 6));
                    gload16(prow[q] + c * 64 + cf * 4, wb + q * 256);
                }
            } else {
#pragma unroll
                for (int j = 0; j < 16; ++j) {
                    const float* rp = xsrc + (size_t)idx[row0w + j] * XD;
                    const int s  = lane >> 2;
                    const int cf = (s & ~7) | ((s & 7) ^ (j & 6));
                    gload4(rp + c * 64 + cf * 4 + (lane & 3), wb + j * 64);
                }
            }
        } else {
            const int jc = c - NCX;
#pragma unroll
            for (int q = 0; q < 4; ++q) {
                const int rl = q * 4 + (lane >> 4);
                const int s  = lane & 15;
                const int cf = (s & ~7) | ((s & 7) ^ (rl & 6));
                gload16(skip + (size_t)(row0w + rl) * SD + jc * 64 + cf * 4,
                        wb + q * 256);
            }
        }
    };

    issue(0);

#pragma unroll
    for (int c = 0; c < NC; ++c) {
        const int kvb = (c < NCX) ? c * 64 : XTILES * 32 + (c - NCX) * 64;
        // B fragments for this chunk (issued BEFORE next DMA so in-order
        // vmcnt retire covers them at the counted wait)
        bf16x8 Bf[2][NT];
#pragma unroll
        for (int tt = 0; tt < 2; ++tt)
#pragma unroll
            for (int nt = 0; nt < NT; ++nt)
                Bf[tt][nt] = *(const bf16x8*)(wtl + kvb + tt * 32 + kg * 8
                                              + nt * 16 * KV);
        if (c + 1 < NC) issue(c + 1);
        wait_vm((c + 1 < NC) ? (((c + 1) < NCX && !XA16) ? 16 : 4) : 0);

        const float* wb = &abuf[wave][c & 1][0];
#pragma unroll
        for (int tt = 0; tt < 2; ++tt) {
            const int s0 = tt * 8 + kg * 2;
            const int sw = (s0 & ~7) | ((s0 & 7) ^ (lr & 6));
            const float* fp = wb + lr * 64 + sw * 4;
            f32x4 lo = *(const f32x4*)fp;
            f32x4 hi = *(const f32x4*)(fp + 4);
            float v[8];
#pragma unroll
            for (int e = 0; e < 4; ++e) { v[e] = lo[e]; v[e + 4] = hi[e]; }
            if (BN && c < NCX) {
                const int kb = c * 64 + tt * 32 + kg * 8;
                f32x4 c0 = *(const f32x4*)(bnsc + kb);
                f32x4 c1 = *(const f32x4*)(bnsc + kb + 4);
                f32x4 h0 = *(const f32x4*)(bnsh + kb);
                f32x4 h1 = *(const f32x4*)(bnsh + kb + 4);
#pragma unroll
                for (int e = 0; e < 4; ++e) {
                    v[e]     = lrelu(fmaf(v[e],     c0[e], h0[e]));
                    v[e + 4] = lrelu(fmaf(v[e + 4], c1[e], h1[e]));
                }
            }
            bf16x8 a;
#pragma unroll
            for (int e = 0; e < 8; ++e) a[e] = f2bf(v[e]);
#pragma unroll
            for (int nt = 0; nt < NT; ++nt)
                acc[nt] = __builtin_amdgcn_mfma_f32_16x16x32_bf16(a, Bf[tt][nt],
                                                                  acc[nt], 0, 0, 0);
        }
    }

    // ---- bias + store ----
#pragma unroll
    for (int nt = 0; nt < NT; ++nt) {
        const int n = n0 + nt * 16 + lr;
        const float bv = (n < NVALID) ? bias[n] : 0.f;
#pragma unroll
        for (int r = 0; r < 4; ++r) acc[nt][r] += bv;
        if (n < NVALID) {
#pragma unroll
            for (int r = 0; r < 4; ++r)
                out[(size_t)(row0w + kg * 4 + r) * OD + n] = acc[nt][r];
        }
    }

    // ---- stats (LDS overlay after all staging consumed) ----
    if (STATS) {
        float* ls = &abuf[0][0][0];
        __syncthreads();
        for (int i = tid; i < 2 * NPAD; i += 256) ls[i] = 0.f;
        __syncthreads();
#pragma unroll
        for (int nt = 0; nt < NT; ++nt) {
            float s = acc[nt][0] + acc[nt][1] + acc[nt][2] + acc[nt][3];
            float q = acc[nt][0]*acc[nt][0] + acc[nt][1]*acc[nt][1]
                    + acc[nt][2]*acc[nt][2] + acc[nt][3]*acc[nt][3];
            s += __shfl_xor(s, 16, 64);
            s += __shfl_xor(s, 32, 64);
            q += __shfl_xor(q, 16, 64);
            q += __shfl_xor(q, 32, 64);
            if (lane < 16) {
                atomicAdd(&ls[nt * 16 + lr], s);
                atomicAdd(&ls[NPAD + nt * 16 + lr], q);
            }
        }
        __syncthreads();
        if (tid < NPAD) {
            atomicAdd(&ssum[n0 + tid], ls[tid]);
            atomicAdd(&ssq[n0 + tid], ls[NPAD + tid]);
        }
    }
}

__global__ void finalize_bn(const float* __restrict__ sum,
                            const float* __restrict__ sq,
                            const float* __restrict__ g,
                            const float* __restrict__ be,
                            float* __restrict__ scale,
                            float* __restrict__ shift,
                            int C, int CPAD, float invN)
{
    int c = blockIdx.x * blockDim.x + threadIdx.x;
    if (c < CPAD) {
        if (c < C) {
            float m   = sum[c] * invN;
            float var = fmaf(-m, m, sq[c] * invN);
            float rs  = rsqrtf(var + EPS);
            float sc  = rs * g[c];
            scale[c] = sc;
            shift[c] = fmaf(-m, sc, be[c]);
        } else {
            scale[c] = 0.f;   // pad channels: force A value to 0
            shift[c] = 0.f;
        }
    }
}

extern "C" void kernel_launch(void* const* d_in, const int* in_sizes, int n_in,
                              void* d_out, int out_size, void* d_ws, size_t ws_size,
                              hipStream_t stream) {
    const float* feats = (const float*)d_in[0];
    const float* skip1 = (const float*)d_in[1];
    const float* skip2 = (const float*)d_in[2];
    const float* skip3 = (const float*)d_in[3];
    const int*   idx1  = (const int*)d_in[4];
    const int*   idx2  = (const int*)d_in[5];
    const int*   idx3  = (const int*)d_in[6];
    const float* W1    = (const float*)d_in[7];
    const float* b1    = (const float*)d_in[8];
    const float* g1    = (const float*)d_in[9];
    const float* be1   = (const float*)d_in[10];
    const float* W2    = (const float*)d_in[11];
    const float* b2    = (const float*)d_in[12];
    const float* g2    = (const float*)d_in[13];
    const float* be2   = (const float*)d_in[14];
    const float* W3    = (const float*)d_in[15];
    const float* b3    = (const float*)d_in[16];

    float* ws   = (float*)d_ws;
    float* sum1 = ws;        float* sq1 = ws + 256;
    float* sc1  = ws + 512;  float* sh1 = ws + 768;   // 192 used
    float* sum2 = ws + 1024; float* sq2 = ws + 1280;
    float* sc2  = ws + 1536; float* sh2 = ws + 1792;
    short* Wt1  = (short*)(ws + 2048);        // 144*800
    short* Wt2  = Wt1 + 144 * 800;            // 64*448
    short* Wt3  = Wt2 + 64 * 448;             // 48*192
    float* y1   = ws + 2048 + (144 * 800 + 64 * 448 + 48 * 192) / 2;  // [16384][192]
    float* y2   = y1 + 16384 * 192;                                   // [65536][64]
    float* outp = (float*)d_out;

    prep<<<450, 256, 0, stream>>>(W1, W2, W3, Wt1, Wt2, Wt3, ws);

    // stage 1: M=16384, x=feats(258, misaligned -> width-4 row-contig),
    // skip3(512), N=129 in 3 n-chunks, y1 padded to 192 cols
    mfma_stage<258, 258, 9, 512, 3, 129, 192, 800, false, false, true>
        <<<dim3(256, 3), 256, 0, stream>>>(feats, skip3, idx1, Wt1, b1,
                                           nullptr, nullptr, y1, sum1, sq1);
    finalize_bn<<<1, 256, 0, stream>>>(sum1, sq1, g1, be1, sc1, sh1,
                                       129, 192, 1.f / 16384.f);

    // stage 2: M=65536, x=y1(192 padded, pad zeroed via BN), skip2(256), N=64
    mfma_stage<192, 192, 6, 256, 4, 64, 64, 448, true, true, true>
        <<<dim3(1024, 1), 256, 0, stream>>>(y1, skip2, idx2, Wt2, b2,
                                            sc1, sh1, y2, sum2, sq2);
    finalize_bn<<<1, 256, 0, stream>>>(sum2, sq2, g2, be2, sc2, sh2,
                                       64, 64, 1.f / 65536.f);

    // stage 3: M=262144, x=y2(64), skip1(128), N=34
    mfma_stage<64, 64, 2, 128, 3, 34, 34, 192, true, true, false>
        <<<dim3(4096, 1), 256, 0, stream>>>(y2, skip1, idx3, Wt3, b3,
                                            sc2, sh2, outp, nullptr, nullptr);
}

// Round 6
// 127.123 us; speedup vs baseline: 1.4828x; 1.2022x over previous
//
#include <hip/hip_runtime.h>

#define EPS 1e-5f
#define SLOPE 0.01f

typedef __attribute__((ext_vector_type(4))) float f32x4;
typedef __attribute__((ext_vector_type(8))) short bf16x8;

__device__ __forceinline__ short f2bf(float f) {
    unsigned u = __float_as_uint(f);
    unsigned r = (u + 0x7FFFu + ((u >> 16) & 1u)) >> 16;
    return (short)r;
}
__device__ __forceinline__ float lrelu(float v) { return v >= 0.f ? v : SLOPE * v; }

__device__ __forceinline__ void gload16(const float* g, float* l) {
    __builtin_amdgcn_global_load_lds(
        (const __attribute__((address_space(1))) unsigned*)g,
        (__attribute__((address_space(3))) unsigned*)l, 16, 0, 0);
}
__device__ __forceinline__ void gload4(const float* g, float* l) {
    __builtin_amdgcn_global_load_lds(
        (const __attribute__((address_space(1))) unsigned*)g,
        (__attribute__((address_space(3))) unsigned*)l, 4, 0, 0);
}
__device__ __forceinline__ void wait_vm(int n) {
    switch (n) {
    case 0:  asm volatile("s_waitcnt vmcnt(0)" ::: "memory"); break;
    case 4:  asm volatile("s_waitcnt vmcnt(4)" ::: "memory"); break;
    case 16: asm volatile("s_waitcnt vmcnt(16)" ::: "memory"); break;
    default: asm volatile("s_waitcnt vmcnt(0)" ::: "memory"); break;
    }
}

// ---------------------------------------------------------------------------
// Wt prep, FRAGMENT-ORDERED: Wt[((t*NT + nt)*64 + lane)*8 + e] = bf16 of
// W[kv][n] with kv = t*32 + (lane>>4)*8 + e, n = nt*16 + (lane&15).
// B-frag loads in the GEMM become base + lane*16B -> fully coalesced.
// Virtual-kv maps (zero rows at pads):
//  S1 (25 tiles, NT=9): kv<258 -> W1 row kv; 258..287 -> 0; 288.. -> W1 row kv-30
//  S2 (14 tiles, NT=4): kv<129 -> W2 row kv; 129..191 -> 0; 192.. -> W2 row kv-63
//  S3 ( 6 tiles, NT=3): kv -> W3 row kv (exact)
// Also zeros the 2048-float stats block.
// ---------------------------------------------------------------------------
__global__ void prep(const float* __restrict__ W1, const float* __restrict__ W2,
                     const float* __restrict__ W3,
                     short* __restrict__ Wt1, short* __restrict__ Wt2,
                     short* __restrict__ Wt3, float* __restrict__ stats)
{
    int id = blockIdx.x * 256 + threadIdx.x;
    if (id < 2048) stats[id] = 0.f;
    {   // S1: 25*9*512 = 115200
        if (id < 115200) {
            int e = id & 7, lane = (id >> 3) & 63, g = id >> 9;
            int t = g / 9, nt = g - t * 9;
            int kv = t * 32 + (lane >> 4) * 8 + e;
            int n  = nt * 16 + (lane & 15);
            float v = 0.f; int ks = -1;
            if (kv < 258) ks = kv; else if (kv >= 288) ks = kv - 30;
            if (ks >= 0 && n < 129) v = W1[ks * 129 + n];
            Wt1[id] = f2bf(v);
        }
    }
    {   // S2: 14*4*512 = 28672
        if (id < 28672) {
            int e = id & 7, lane = (id >> 3) & 63, g = id >> 9;
            int t = g >> 2, nt = g & 3;
            int kv = t * 32 + (lane >> 4) * 8 + e;
            int n  = nt * 16 + (lane & 15);
            float v = 0.f; int ks = -1;
            if (kv < 129) ks = kv; else if (kv >= 192) ks = kv - 63;
            if (ks >= 0) v = W2[ks * 64 + n];
            Wt2[id] = f2bf(v);
        }
    }
    {   // S3: 6*3*512 = 9216
        if (id < 9216) {
            int e = id & 7, lane = (id >> 3) & 63, g = id >> 9;
            int t = g / 3, nt = g - t * 3;
            int kv = t * 32 + (lane >> 4) * 8 + e;
            int n  = nt * 16 + (lane & 15);
            float v = (n < 34) ? W3[kv * 34 + n] : 0.f;
            Wt3[id] = f2bf(v);
        }
    }
}

// ---------------------------------------------------------------------------
// MFMA stage. 4 waves/block, wave owns 16 rows, single n-pass (NT n-tiles).
// K in 64-float chunks staged to per-wave LDS (double-buffered) via
// global_load_lds with row-contiguous 256B spans + XOR source swizzle;
// counted per-wave vmcnt, no intra-loop barriers. B-frags are coalesced
// lane-contiguous loads from fragment-ordered Wt, issued before the next
// chunk's DMA so the counted wait covers them (in-order retire).
// ---------------------------------------------------------------------------
template<int XD, int XVALID, int XTILES, int SD, int NT, int NVALID, int OD,
         bool XA16, bool BN, bool STATS, int MINW>
__global__ __launch_bounds__(256, MINW)
void mfma_stage(const float* __restrict__ xsrc, const float* __restrict__ skip,
                const int* __restrict__ idx, const short* __restrict__ Wt,
                const float* __restrict__ bias,
                const float* __restrict__ bnsc, const float* __restrict__ bnsh,
                float* __restrict__ out, float* __restrict__ ssum,
                float* __restrict__ ssq)
{
    constexpr int NCX = XVALID / 64;
    constexpr int NCS = SD / 64;
    constexpr int NC  = NCX + NCS;
    constexpr bool HASPART = (XVALID % 64) != 0;
    constexpr int NPAD = NT * 16;

    __shared__ __align__(16) float abuf[4][2][1024];   // 32 KB

    const int tid  = threadIdx.x;
    const int wave = tid >> 6, lane = tid & 63;
    const int lr = lane & 15;
    const int kg = lane >> 4;
    const int row0w = (blockIdx.x * 4 + wave) * 16;
    const short* wtf = Wt + (lane << 3);

    const float* prow[4];
    if (XA16) {
#pragma unroll
        for (int q = 0; q < 4; ++q)
            prow[q] = xsrc + (size_t)idx[row0w + q * 4 + (lane >> 4)] * XD;
    }

    f32x4 acc[NT];
#pragma unroll
    for (int nt = 0; nt < NT; ++nt) acc[nt] = (f32x4){0.f, 0.f, 0.f, 0.f};

    // ---- partial x tile (stage 1 only) ----
    if (HASPART) {
        const float* xr = xsrc + (size_t)idx[row0w + lr] * XD;
        constexpr int kb = (XTILES - 1) * 32;
        float v[8];
#pragma unroll
        for (int e = 0; e < 8; ++e) {
            int ks = kb + kg * 8 + e;
            float f = 0.f;
            if (ks < XVALID) {
                f = xr[ks];
                if (BN) f = lrelu(fmaf(f, bnsc[ks], bnsh[ks]));
            }
            v[e] = f;
        }
        bf16x8 a;
#pragma unroll
        for (int e = 0; e < 8; ++e) a[e] = f2bf(v[e]);
#pragma unroll
        for (int nt = 0; nt < NT; ++nt) {
            bf16x8 b = *(const bf16x8*)(wtf + (((XTILES - 1) * NT + nt) << 9));
            acc[nt] = __builtin_amdgcn_mfma_f32_16x16x32_bf16(a, b, acc[nt], 0, 0, 0);
        }
    }

    auto issue = [&](int c) {
        float* wb = &abuf[wave][c & 1][0];
        if (c < NCX) {
            if (XA16) {
#pragma unroll
                for (int q = 0; q < 4; ++q) {
                    const int rl = q * 4 + (lane >> 4);
                    const int s  = lane & 15;
                    const int cf = (s & ~7) | ((s & 7) ^ (rl & 6));
                    gload16(prow[q] + c * 64 + cf * 4, wb + q * 256);
                }
            } else {
#pragma unroll
                for (int j = 0; j < 16; ++j) {
                    const float* rp = xsrc + (size_t)idx[row0w + j] * XD;
                    const int s  = lane >> 2;
                    const int cf = (s & ~7) | ((s & 7) ^ (j & 6));
                    gload4(rp + c * 64 + cf * 4 + (lane & 3), wb + j * 64);
                }
            }
        } else {
            const int jc = c - NCX;
#pragma unroll
            for (int q = 0; q < 4; ++q) {
                const int rl = q * 4 + (lane >> 4);
                const int s  = lane & 15;
                const int cf = (s & ~7) | ((s & 7) ^ (rl & 6));
                gload16(skip + (size_t)(row0w + rl) * SD + jc * 64 + cf * 4,
                        wb + q * 256);
            }
        }
    };

    issue(0);

#pragma unroll
    for (int c = 0; c < NC; ++c) {
        // B fragments (coalesced, L2-hot), BEFORE next DMA issue
        bf16x8 Bf[2][NT];
#pragma unroll
        for (int tt = 0; tt < 2; ++tt) {
            const int tv = (c < NCX) ? (2 * c + tt) : (XTILES + 2 * (c - NCX) + tt);
#pragma unroll
            for (int nt = 0; nt < NT; ++nt)
                Bf[tt][nt] = *(const bf16x8*)(wtf + ((tv * NT + nt) << 9));
        }
        if (c + 1 < NC) issue(c + 1);
        wait_vm((c + 1 < NC) ? (((c + 1) < NCX && !XA16) ? 16 : 4) : 0);

        const float* wb = &abuf[wave][c & 1][0];
#pragma unroll
        for (int tt = 0; tt < 2; ++tt) {
            const int s0 = tt * 8 + kg * 2;
            const int sw = (s0 & ~7) | ((s0 & 7) ^ (lr & 6));
            const float* fp = wb + lr * 64 + sw * 4;
            f32x4 lo = *(const f32x4*)fp;
            f32x4 hi = *(const f32x4*)(fp + 4);
            float v[8];
#pragma unroll
            for (int e = 0; e < 4; ++e) { v[e] = lo[e]; v[e + 4] = hi[e]; }
            if (BN && c < NCX) {
                const int kb = c * 64 + tt * 32 + kg * 8;
                f32x4 c0 = *(const f32x4*)(bnsc + kb);
                f32x4 c1 = *(const f32x4*)(bnsc + kb + 4);
                f32x4 h0 = *(const f32x4*)(bnsh + kb);
                f32x4 h1 = *(const f32x4*)(bnsh + kb + 4);
#pragma unroll
                for (int e = 0; e < 4; ++e) {
                    v[e]     = lrelu(fmaf(v[e],     c0[e], h0[e]));
                    v[e + 4] = lrelu(fmaf(v[e + 4], c1[e], h1[e]));
                }
            }
            bf16x8 a;
#pragma unroll
            for (int e = 0; e < 8; ++e) a[e] = f2bf(v[e]);
#pragma unroll
            for (int nt = 0; nt < NT; ++nt)
                acc[nt] = __builtin_amdgcn_mfma_f32_16x16x32_bf16(a, Bf[tt][nt],
                                                                  acc[nt], 0, 0, 0);
        }
    }

    // ---- bias + store ----
#pragma unroll
    for (int nt = 0; nt < NT; ++nt) {
        const int n = nt * 16 + lr;
        const float bv = (n < NVALID) ? bias[n] : 0.f;
#pragma unroll
        for (int r = 0; r < 4; ++r) acc[nt][r] += bv;
        if (n < NVALID) {
#pragma unroll
            for (int r = 0; r < 4; ++r)
                out[(size_t)(row0w + kg * 4 + r) * OD + n] = acc[nt][r];
        }
    }

    // ---- stats ----
    if (STATS) {
        float* ls = &abuf[0][0][0];
        __syncthreads();
        for (int i = tid; i < 2 * NPAD; i += 256) ls[i] = 0.f;
        __syncthreads();
#pragma unroll
        for (int nt = 0; nt < NT; ++nt) {
            float s = acc[nt][0] + acc[nt][1] + acc[nt][2] + acc[nt][3];
            float q = acc[nt][0]*acc[nt][0] + acc[nt][1]*acc[nt][1]
                    + acc[nt][2]*acc[nt][2] + acc[nt][3]*acc[nt][3];
            s += __shfl_xor(s, 16, 64);
            s += __shfl_xor(s, 32, 64);
            q += __shfl_xor(q, 16, 64);
            q += __shfl_xor(q, 32, 64);
            if (lane < 16) {
                atomicAdd(&ls[nt * 16 + lr], s);
                atomicAdd(&ls[NPAD + nt * 16 + lr], q);
            }
        }
        __syncthreads();
        for (int i = tid; i < NPAD; i += 256) {
            atomicAdd(&ssum[i], ls[i]);
            atomicAdd(&ssq[i], ls[NPAD + i]);
        }
    }
}

__global__ void finalize_bn(const float* __restrict__ sum,
                            const float* __restrict__ sq,
                            const float* __restrict__ g,
                            const float* __restrict__ be,
                            float* __restrict__ scale,
                            float* __restrict__ shift,
                            int C, int CPAD, float invN)
{
    int c = blockIdx.x * blockDim.x + threadIdx.x;
    if (c < CPAD) {
        if (c < C) {
            float m   = sum[c] * invN;
            float var = fmaf(-m, m, sq[c] * invN);
            float rs  = rsqrtf(var + EPS);
            float sc  = rs * g[c];
            scale[c] = sc;
            shift[c] = fmaf(-m, sc, be[c]);
        } else {
            scale[c] = 0.f;   // pad channels: force A value to 0
            shift[c] = 0.f;
        }
    }
}

extern "C" void kernel_launch(void* const* d_in, const int* in_sizes, int n_in,
                              void* d_out, int out_size, void* d_ws, size_t ws_size,
                              hipStream_t stream) {
    const float* feats = (const float*)d_in[0];
    const float* skip1 = (const float*)d_in[1];
    const float* skip2 = (const float*)d_in[2];
    const float* skip3 = (const float*)d_in[3];
    const int*   idx1  = (const int*)d_in[4];
    const int*   idx2  = (const int*)d_in[5];
    const int*   idx3  = (const int*)d_in[6];
    const float* W1    = (const float*)d_in[7];
    const float* b1    = (const float*)d_in[8];
    const float* g1    = (const float*)d_in[9];
    const float* be1   = (const float*)d_in[10];
    const float* W2    = (const float*)d_in[11];
    const float* b2    = (const float*)d_in[12];
    const float* g2    = (const float*)d_in[13];
    const float* be2   = (const float*)d_in[14];
    const float* W3    = (const float*)d_in[15];
    const float* b3    = (const float*)d_in[16];

    float* ws   = (float*)d_ws;
    float* sum1 = ws;        float* sq1 = ws + 256;
    float* sc1  = ws + 512;  float* sh1 = ws + 768;   // 192 used
    float* sum2 = ws + 1024; float* sq2 = ws + 1280;
    float* sc2  = ws + 1536; float* sh2 = ws + 1792;
    short* Wt1  = (short*)(ws + 2048);        // 115200 frag-ordered
    short* Wt2  = Wt1 + 115200;               // 28672
    short* Wt3  = Wt2 + 28672;                // 9216
    float* y1   = ws + 2048 + (115200 + 28672 + 9216) / 2;   // [16384][192]
    float* y2   = y1 + 16384 * 192;                          // [65536][64]
    float* outp = (float*)d_out;

    prep<<<450, 256, 0, stream>>>(W1, W2, W3, Wt1, Wt2, Wt3, ws);

    // stage 1: M=16384, feats(258, width-4 staging) + skip3(512), N=129,
    // SINGLE n-pass (NT=9), 256 blocks (1/CU)
    mfma_stage<258, 258, 9, 512, 9, 129, 192, false, false, true, 1>
        <<<256, 256, 0, stream>>>(feats, skip3, idx1, Wt1, b1,
                                  nullptr, nullptr, y1, sum1, sq1);
    finalize_bn<<<1, 256, 0, stream>>>(sum1, sq1, g1, be1, sc1, sh1,
                                       129, 192, 1.f / 16384.f);

    // stage 2: M=65536, y1(192 padded) + skip2(256), N=64
    mfma_stage<192, 192, 6, 256, 4, 64, 64, true, true, true, 4>
        <<<1024, 256, 0, stream>>>(y1, skip2, idx2, Wt2, b2,
                                   sc1, sh1, y2, sum2, sq2);
    finalize_bn<<<1, 256, 0, stream>>>(sum2, sq2, g2, be2, sc2, sh2,
                                       64, 64, 1.f / 65536.f);

    // stage 3: M=262144, y2(64) + skip1(128), N=34
    mfma_stage<64, 64, 2, 128, 3, 34, 34, true, true, false, 4>
        <<<4096, 256, 0, stream>>>(y2, skip1, idx3, Wt3, b3,
                                   sc2, sh2, outp, nullptr, nullptr);
}

// Round 7
// 122.468 us; speedup vs baseline: 1.5392x; 1.0380x over previous
//
#include <hip/hip_runtime.h>

#define EPS 1e-5f
#define SLOPE 0.01f

typedef __attribute__((ext_vector_type(4))) float f32x4;
typedef __attribute__((ext_vector_type(8))) short bf16x8;

__device__ __forceinline__ short f2bf(float f) {
    unsigned u = __float_as_uint(f);
    unsigned r = (u + 0x7FFFu + ((u >> 16) & 1u)) >> 16;
    return (short)r;
}
__device__ __forceinline__ float lrelu(float v) { return v >= 0.f ? v : SLOPE * v; }

__device__ __forceinline__ void gload16(const float* g, float* l) {
    __builtin_amdgcn_global_load_lds(
        (const __attribute__((address_space(1))) unsigned*)g,
        (__attribute__((address_space(3))) unsigned*)l, 16, 0, 0);
}
__device__ __forceinline__ void gload4(const float* g, float* l) {
    __builtin_amdgcn_global_load_lds(
        (const __attribute__((address_space(1))) unsigned*)g,
        (__attribute__((address_space(3))) unsigned*)l, 4, 0, 0);
}

#define WCASE(N) case N: asm volatile("s_waitcnt vmcnt(" #N ")" ::: "memory"); break;
__device__ __forceinline__ void wait_vm(int n) {
    switch (n) {
    WCASE(0) WCASE(1) WCASE(2) WCASE(3) WCASE(4) WCASE(5) WCASE(6) WCASE(7)
    WCASE(8) WCASE(9) WCASE(10) WCASE(11) WCASE(12) WCASE(13) WCASE(14) WCASE(15)
    WCASE(16) WCASE(17) WCASE(18) WCASE(19) WCASE(20) WCASE(21) WCASE(22) WCASE(23)
    WCASE(24) WCASE(25) WCASE(26) WCASE(27) WCASE(28) WCASE(29) WCASE(30) WCASE(31)
    WCASE(32) WCASE(33) WCASE(34) WCASE(35) WCASE(36) WCASE(37) WCASE(38) WCASE(39)
    WCASE(40) WCASE(41) WCASE(42) WCASE(43) WCASE(44) WCASE(45) WCASE(46) WCASE(47)
    WCASE(48) WCASE(49) WCASE(50) WCASE(51) WCASE(52) WCASE(53) WCASE(54) WCASE(55)
    WCASE(56) WCASE(57) WCASE(58) WCASE(59) WCASE(60) WCASE(61) WCASE(62) WCASE(63)
    default: asm volatile("s_waitcnt vmcnt(0)" ::: "memory"); break;
    }
}

// ---------------------------------------------------------------------------
// Wt prep, FRAGMENT-ORDERED: Wt[((tv*NT + nt)*64 + lane)*8 + e] = bf16 of
// W[kv][n], kv = tv*32 + (lane>>4)*8 + e, n = nt*16 + (lane&15).
// 64-aligned virtual-kv maps (zero rows at pads):
//  S1 (26 tiles, NT=9): kv<258 -> W1 row kv; 258..319 -> 0; >=320 -> row kv-62
//  S2 (14 tiles, NT=4): kv<129 -> W2 row kv; 129..191 -> 0; >=192 -> row kv-63
//  S3 ( 6 tiles, NT=3): kv -> W3 row kv (exact)
// Also zeros the 2048-float stats block.
// ---------------------------------------------------------------------------
__global__ void prep(const float* __restrict__ W1, const float* __restrict__ W2,
                     const float* __restrict__ W3,
                     short* __restrict__ Wt1, short* __restrict__ Wt2,
                     short* __restrict__ Wt3, float* __restrict__ stats)
{
    int id = blockIdx.x * 256 + threadIdx.x;
    if (id < 2048) stats[id] = 0.f;
    if (id < 26 * 9 * 512) {
        int e = id & 7, lane = (id >> 3) & 63, g = id >> 9;
        int t = g / 9, nt = g - t * 9;
        int kv = t * 32 + (lane >> 4) * 8 + e;
        int n  = nt * 16 + (lane & 15);
        float v = 0.f; int ks = -1;
        if (kv < 258) ks = kv; else if (kv >= 320) ks = kv - 62;
        if (ks >= 0 && n < 129) v = W1[ks * 129 + n];
        Wt1[id] = f2bf(v);
    }
    if (id < 14 * 4 * 512) {
        int e = id & 7, lane = (id >> 3) & 63, g = id >> 9;
        int t = g >> 2, nt = g & 3;
        int kv = t * 32 + (lane >> 4) * 8 + e;
        int n  = nt * 16 + (lane & 15);
        float v = 0.f; int ks = -1;
        if (kv < 129) ks = kv; else if (kv >= 192) ks = kv - 63;
        if (ks >= 0) v = W2[ks * 64 + n];
        Wt2[id] = f2bf(v);
    }
    if (id < 6 * 3 * 512) {
        int e = id & 7, lane = (id >> 3) & 63, g = id >> 9;
        int t = g / 3, nt = g - t * 3;
        int kv = t * 32 + (lane >> 4) * 8 + e;
        int n  = nt * 16 + (lane & 15);
        float v = (n < 34) ? W3[kv * 34 + n] : 0.f;
        Wt3[id] = f2bf(v);
    }
}

// ---------------------------------------------------------------------------
// MFMA stage. 4 waves/block, wave owns 16 rows, single n-pass.
// 2-deep LDS staging (NBUF=3, per-wave private regions, no K-loop barriers),
// B-frags triple-buffered in regs with >=1 iteration of slack (or fully
// preloaded when PRELB). Counted vmcnt waits count ONLY our DMA instructions
// (undercount-safe vs compiler-scheduled loads). BN tables read from LDS
// (lgkmcnt path - cannot perturb vmcnt).
// ---------------------------------------------------------------------------
template<int XD, int SD, int NCX, int NCS, int NT, int NVALID, int OD,
         bool XA16, int XCLAMP, bool BN, bool STATS, bool PRELB, int MINW>
__global__ __launch_bounds__(256, MINW)
void mfma_stage(const float* __restrict__ xsrc, const float* __restrict__ skip,
                const int* __restrict__ idx, const short* __restrict__ Wt,
                const float* __restrict__ bias,
                const float* __restrict__ bnsc, const float* __restrict__ bnsh,
                float* __restrict__ out, float* __restrict__ ssum,
                float* __restrict__ ssq)
{
    constexpr int NC = NCX + NCS;
    constexpr int T = 2 * NC;
    constexpr int NPAD = NT * 16;

    __shared__ __align__(16) float abuf[4][3][1024];          // 48 KB
    __shared__ __align__(16) float bnl[BN ? 2 * NCX * 64 : 4];

    const int tid  = threadIdx.x;
    const int wave = tid >> 6, lane = tid & 63;
    const int lr = lane & 15;
    const int kg = lane >> 4;
    const int row0w = (blockIdx.x * 4 + wave) * 16;
    const short* wtf = Wt + (lane << 3);

    // BN tables -> LDS (before any DMA; barrier's implicit drain is harmless)
    if (BN) {
        for (int i = tid; i < NCX * 64; i += 256) {
            bnl[i] = bnsc[i];
            bnl[NCX * 64 + i] = bnsh[i];
        }
        __syncthreads();
    }

    // row pointers
    const float* prow[4];
    const float* rp16[16];
    if (XA16) {
#pragma unroll
        for (int q = 0; q < 4; ++q)
            prow[q] = xsrc + (size_t)idx[row0w + q * 4 + kg] * XD;
    } else {
#pragma unroll
        for (int j = 0; j < 16; ++j)
            rp16[j] = xsrc + (size_t)idx[row0w + j] * XD;
    }

    f32x4 acc[NT];
#pragma unroll
    for (int nt = 0; nt < NT; ++nt) acc[nt] = (f32x4){0.f, 0.f, 0.f, 0.f};

    auto sopsf = [](int c) { return (c < NCX && !XA16) ? 16 : 4; };

    auto issue = [&](int c) {
        float* wb = &abuf[wave][c % 3][0];
        if (c < NCX) {
            if (XA16) {
#pragma unroll
                for (int q = 0; q < 4; ++q) {
                    const int rl = q * 4 + kg;
                    const int s  = lane & 15;
                    const int cf = (s & ~7) | ((s & 7) ^ (rl & 6));
                    gload16(prow[q] + c * 64 + cf * 4, wb + q * 256);
                }
            } else {
#pragma unroll
                for (int j = 0; j < 16; ++j) {
                    const int s  = lane >> 2;
                    const int cf = (s & ~7) | ((s & 7) ^ (j & 6));
                    int col = c * 64 + cf * 4 + (lane & 3);
                    if (XCLAMP > 0 && c == NCX - 1) col = min(col, XCLAMP - 1);
                    gload4(rp16[j] + col, wb + j * 64);
                }
            }
        } else {
            const int jc = c - NCX;
#pragma unroll
            for (int q = 0; q < 4; ++q) {
                const int rl = q * 4 + kg;
                const int s  = lane & 15;
                const int cf = (s & ~7) | ((s & 7) ^ (rl & 6));
                gload16(skip + (size_t)(row0w + rl) * SD + jc * 64 + cf * 4,
                        wb + q * 256);
            }
        }
    };

    // B-fragment registers
    bf16x8 Bp[PRELB ? T * NT : 1];
    bf16x8 Bf[PRELB ? 1 : 3][2][NT];

    if (PRELB) {   // all B first, so counted waits can keep staging in flight
#pragma unroll
        for (int tv = 0; tv < T; ++tv)
#pragma unroll
            for (int nt = 0; nt < NT; ++nt)
                Bp[tv * NT + nt] = *(const bf16x8*)(wtf + ((tv * NT + nt) << 9));
    }

    issue(0);
    if (NC > 1) issue(1);

    if (!PRELB) {
#pragma unroll
        for (int tt = 0; tt < 2; ++tt)
#pragma unroll
            for (int nt = 0; nt < NT; ++nt) {
                Bf[0][tt][nt] = *(const bf16x8*)(wtf + ((tt * NT + nt) << 9));
                if (NC > 1)
                    Bf[1][tt][nt] = *(const bf16x8*)(wtf + (((2 + tt) * NT + nt) << 9));
            }
    }

#pragma unroll
    for (int c = 0; c < NC; ++c) {
        if (c + 2 < NC) issue(c + 2);
        // count only our DMAs: chunks c+1, c+2 still allowed in flight
        wait_vm(((c + 1 < NC) ? sopsf(c + 1) : 0) + ((c + 2 < NC) ? sopsf(c + 2) : 0));
        if (!PRELB && c + 2 < NC) {   // load B(c+2) AFTER the wait -> 2-iter slack
#pragma unroll
            for (int tt = 0; tt < 2; ++tt)
#pragma unroll
                for (int nt = 0; nt < NT; ++nt)
                    Bf[(c + 2) % 3][tt][nt] =
                        *(const bf16x8*)(wtf + (((2 * (c + 2) + tt) * NT + nt) << 9));
        }

        const float* wb = &abuf[wave][c % 3][0];
#pragma unroll
        for (int tt = 0; tt < 2; ++tt) {
            const int s0 = tt * 8 + kg * 2;
            const int sw = (s0 & ~7) | ((s0 & 7) ^ (lr & 6));
            const float* fp = wb + lr * 64 + sw * 4;
            f32x4 lo = *(const f32x4*)fp;
            f32x4 hi = *(const f32x4*)(fp + 4);
            float v[8];
#pragma unroll
            for (int e = 0; e < 4; ++e) { v[e] = lo[e]; v[e + 4] = hi[e]; }
            if (BN && c < NCX) {
                const int kb = c * 64 + tt * 32 + kg * 8;
                f32x4 c0 = *(const f32x4*)&bnl[kb];
                f32x4 c1 = *(const f32x4*)&bnl[kb + 4];
                f32x4 h0 = *(const f32x4*)&bnl[NCX * 64 + kb];
                f32x4 h1 = *(const f32x4*)&bnl[NCX * 64 + kb + 4];
#pragma unroll
                for (int e = 0; e < 4; ++e) {
                    v[e]     = lrelu(fmaf(v[e],     c0[e], h0[e]));
                    v[e + 4] = lrelu(fmaf(v[e + 4], c1[e], h1[e]));
                }
            }
            bf16x8 a;
#pragma unroll
            for (int e = 0; e < 8; ++e) a[e] = f2bf(v[e]);
#pragma unroll
            for (int nt = 0; nt < NT; ++nt) {
                bf16x8 b;
                if (PRELB) b = Bp[(2 * c + tt) * NT + nt];
                else       b = Bf[c % 3][tt][nt];
                acc[nt] = __builtin_amdgcn_mfma_f32_16x16x32_bf16(a, b, acc[nt], 0, 0, 0);
            }
        }
    }

    // ---- bias + store ----
#pragma unroll
    for (int nt = 0; nt < NT; ++nt) {
        const int n = nt * 16 + lr;
        const float bv = (n < NVALID) ? bias[n] : 0.f;
#pragma unroll
        for (int r = 0; r < 4; ++r) acc[nt][r] += bv;
        if (n < NVALID) {
#pragma unroll
            for (int r = 0; r < 4; ++r)
                out[(size_t)(row0w + kg * 4 + r) * OD + n] = acc[nt][r];
        }
    }

    // ---- stats ----
    if (STATS) {
        float* ls = &abuf[0][0][0];
        __syncthreads();
        for (int i = tid; i < 2 * NPAD; i += 256) ls[i] = 0.f;
        __syncthreads();
#pragma unroll
        for (int nt = 0; nt < NT; ++nt) {
            float s = acc[nt][0] + acc[nt][1] + acc[nt][2] + acc[nt][3];
            float q = acc[nt][0]*acc[nt][0] + acc[nt][1]*acc[nt][1]
                    + acc[nt][2]*acc[nt][2] + acc[nt][3]*acc[nt][3];
            s += __shfl_xor(s, 16, 64);
            s += __shfl_xor(s, 32, 64);
            q += __shfl_xor(q, 16, 64);
            q += __shfl_xor(q, 32, 64);
            if (lane < 16) {
                atomicAdd(&ls[nt * 16 + lr], s);
                atomicAdd(&ls[NPAD + nt * 16 + lr], q);
            }
        }
        __syncthreads();
        for (int i = tid; i < NPAD; i += 256) {
            atomicAdd(&ssum[i], ls[i]);
            atomicAdd(&ssq[i], ls[NPAD + i]);
        }
    }
}

__global__ void finalize_bn(const float* __restrict__ sum,
                            const float* __restrict__ sq,
                            const float* __restrict__ g,
                            const float* __restrict__ be,
                            float* __restrict__ scale,
                            float* __restrict__ shift,
                            int C, int CPAD, float invN)
{
    int c = blockIdx.x * blockDim.x + threadIdx.x;
    if (c < CPAD) {
        if (c < C) {
            float m   = sum[c] * invN;
            float var = fmaf(-m, m, sq[c] * invN);
            float rs  = rsqrtf(var + EPS);
            float sc  = rs * g[c];
            scale[c] = sc;
            shift[c] = fmaf(-m, sc, be[c]);
        } else {
            scale[c] = 0.f;
            shift[c] = 0.f;
        }
    }
}

extern "C" void kernel_launch(void* const* d_in, const int* in_sizes, int n_in,
                              void* d_out, int out_size, void* d_ws, size_t ws_size,
                              hipStream_t stream) {
    const float* feats = (const float*)d_in[0];
    const float* skip1 = (const float*)d_in[1];
    const float* skip2 = (const float*)d_in[2];
    const float* skip3 = (const float*)d_in[3];
    const int*   idx1  = (const int*)d_in[4];
    const int*   idx2  = (const int*)d_in[5];
    const int*   idx3  = (const int*)d_in[6];
    const float* W1    = (const float*)d_in[7];
    const float* b1    = (const float*)d_in[8];
    const float* g1    = (const float*)d_in[9];
    const float* be1   = (const float*)d_in[10];
    const float* W2    = (const float*)d_in[11];
    const float* b2    = (const float*)d_in[12];
    const float* g2    = (const float*)d_in[13];
    const float* be2   = (const float*)d_in[14];
    const float* W3    = (const float*)d_in[15];
    const float* b3    = (const float*)d_in[16];

    float* ws   = (float*)d_ws;
    float* sum1 = ws;        float* sq1 = ws + 256;
    float* sc1  = ws + 512;  float* sh1 = ws + 768;   // 192 used
    float* sum2 = ws + 1024; float* sq2 = ws + 1280;
    float* sc2  = ws + 1536; float* sh2 = ws + 1792;
    short* Wt1  = (short*)(ws + 2048);        // 26*9*512 = 119808
    short* Wt2  = Wt1 + 119808;               // 14*4*512 = 28672
    short* Wt3  = Wt2 + 28672;                // 6*3*512  = 9216
    float* y1   = ws + 2048 + (119808 + 28672 + 9216) / 2;   // [16384][192]
    float* y2   = y1 + 16384 * 192;                          // [65536][64]
    float* outp = (float*)d_out;

    prep<<<468, 256, 0, stream>>>(W1, W2, W3, Wt1, Wt2, Wt3, ws);

    // stage 1: M=16384, feats(258 -> 5 chunks, clamp@258) + skip3(512 -> 8),
    // N=129 single pass (NT=9), 256 blocks
    mfma_stage<258, 512, 5, 8, 9, 129, 192, false, 258, false, true, false, 1>
        <<<256, 256, 0, stream>>>(feats, skip3, idx1, Wt1, b1,
                                  nullptr, nullptr, y1, sum1, sq1);
    finalize_bn<<<1, 256, 0, stream>>>(sum1, sq1, g1, be1, sc1, sh1,
                                       129, 192, 1.f / 16384.f);

    // stage 2: M=65536, y1(192 -> 3 chunks) + skip2(256 -> 4), N=64
    mfma_stage<192, 256, 3, 4, 4, 64, 64, true, 0, true, true, false, 3>
        <<<1024, 256, 0, stream>>>(y1, skip2, idx2, Wt2, b2,
                                   sc1, sh1, y2, sum2, sq2);
    finalize_bn<<<1, 256, 0, stream>>>(sum2, sq2, g2, be2, sc2, sh2,
                                       64, 64, 1.f / 65536.f);

    // stage 3: M=262144, y2(64 -> 1 chunk) + skip1(128 -> 2), N=34, B preloaded
    mfma_stage<64, 128, 1, 2, 3, 34, 34, true, 0, true, false, true, 3>
        <<<4096, 256, 0, stream>>>(y2, skip1, idx3, Wt3, b3,
                                   sc2, sh2, outp, nullptr, nullptr);
}